// Round 16
// baseline (159.892 us; speedup 1.0000x reference)
//
#include <hip/hip_runtime.h>
#include <math.h>

typedef short short8 __attribute__((ext_vector_type(8)));
typedef float fx4 __attribute__((ext_vector_type(4)));
typedef float fx16 __attribute__((ext_vector_type(16)));
typedef unsigned short ushort;
typedef unsigned int uint;
typedef uint uint2v __attribute__((ext_vector_type(2)));

#define MFMA16(a, b, c) __builtin_amdgcn_mfma_f32_16x16x32_bf16(a, b, c, 0, 0, 0)
#define MFMA32(a, b, c) __builtin_amdgcn_mfma_f32_32x32x16_bf16(a, b, c, 0, 0, 0)

// segments: len {2048,2048,4096}, dil {1,2,4}; q rows packed at [0,2048,4096];
// k/v rows (dilated) packed at [0,2048,3072], total 4096.
// Q pre-scaled by (1/8)*log2(e); shiftless log2-domain softmax (P=exp2(S),
// uniform P scale cancels in O = P.V / P.1; |S|<128 always).
// R14 lesson: dispatch is round-robin (bid -> CU bid%256); keep simple maps.
// R16: GEMMs use BK=32 -> LDS 48KB/block -> 3 blocks/CU co-residency
// (was 96KB -> 1 block/CU, no TLP to hide the 2-phase barrier stalls).
#define QSCALE 0.180336880f

#define BAR() do { asm volatile("" ::: "memory"); __builtin_amdgcn_s_barrier(); asm volatile("" ::: "memory"); } while (0)
#define VMCNT(n) asm volatile("s_waitcnt vmcnt(" #n ")" ::: "memory")

__device__ __forceinline__ ushort f2bf(float f) {
    union { float f; uint u; } v; v.f = f;
    uint r = v.u + 0x7fffu + ((v.u >> 16) & 1u);
    return (ushort)(r >> 16);
}

__device__ __forceinline__ float exp2f_fast(float x) {
    float r; asm("v_exp_f32 %0, %1" : "=v"(r) : "v"(x)); return r;
}

__device__ __forceinline__ uint cvt_pk_bf16(float lo, float hi) {
    uint r; asm("v_cvt_pk_bf16_f32 %0, %1, %2" : "=v"(r) : "v"(lo), "v"(hi)); return r;
}

__device__ __forceinline__ short8 mk8(uint a, uint b, uint c, uint d) {
    union { uint u[4]; short8 s; } x; x.u[0] = a; x.u[1] = b; x.u[2] = c; x.u[3] = d; return x.s;
}

__device__ __forceinline__ void gl_lds16(const void* g, void* l) {
    __builtin_amdgcn_global_load_lds(
        (const __attribute__((address_space(1))) void*)g,
        (__attribute__((address_space(3))) void*)l, 16, 0, 0);
}

// ---- scratch (static device globals; fully rewritten every call) ----
__device__ ushort g_XB[8192 * 1024];      // x bf16 [s][k]
__device__ ushort g_WQB[3072 * 1024];     // Wqkv bf16 [n][k]
__device__ ushort g_WOB[1024 * 1024];     // Wout bf16 [n][k]
__device__ ushort g_QSEG[16 * 8192 * 64]; // [h][qrow][d], permuted, scaled by QSCALE
__device__ ushort g_KSEG[16 * 4096 * 64]; // [h][krow][d], permuted+dilated
__device__ ushort g_VSEG[16 * 4096 * 64]; // [h][krow][d]
__device__ ushort g_VT[16 * 64 * 4096];   // [h][d][krow]  (V transposed)
__device__ ushort g_ATTN[8192 * 1024];    // [qrow][h*64+d] bf16 (permuted row space)
__device__ int g_QROW[8192];              // s -> permuted q row (global)
__device__ int g_KVROW[8192];             // s -> dilated k/v row (global) or -1
__device__ int g_KVSRC[4096];             // packed kv row -> source s (inverse of KVROW)

// ---------------- merged cvt (f32->bf16) + Hilbert perm kernel ----------------
__global__ __launch_bounds__(1024) void cvtperm_kernel(const float* __restrict__ x,
                                                       const float* __restrict__ wq,
                                                       const float* __restrict__ wo) {
    __shared__ int perm_lds[4096];
    __shared__ int inv_lds[4096];
    __shared__ int sc[1024];
    int b = blockIdx.x;
    int tid = threadIdx.x;
    if (b >= 3) {
        int idx = (b - 3) * 1024 + tid;
        const int NX = 8192 * 1024 / 4, NQ = 3072 * 1024 / 4;
        const float* s; ushort* d; int rel;
        if (idx < NX)           { s = x;  d = g_XB;  rel = idx; }
        else if (idx < NX + NQ) { s = wq; d = g_WQB; rel = idx - NX; }
        else                    { s = wo; d = g_WOB; rel = idx - NX - NQ; }
        fx4 v = *(const fx4*)(s + (long)rel * 4);
        uint lo = f2bf(v[0]) | ((uint)f2bf(v[1]) << 16);
        uint hi = f2bf(v[2]) | ((uint)f2bf(v[3]) << 16);
        uint2v w; w[0] = lo; w[1] = hi;
        *(uint2v*)(d + (long)rel * 4) = w;
        return;
    }
    int seg = b;
    int L     = (seg == 2) ? 4096 : 2048;
    int dil   = (seg == 0) ? 1 : (seg == 1) ? 2 : 4;
    int pos   = (seg == 0) ? 0 : (seg == 1) ? 2048 : 4096;
    int kbase = (seg == 0) ? 0 : (seg == 1) ? 2048 : 3072;

    int lin[4]; int flg[4]; int cnt = 0;
    #pragma unroll
    for (int c = 0; c < 4; c++) {
        int d = tid * 4 + c;
        int px = 0, py = 0, t = d;
        for (int s = 1; s < 64; s <<= 1) {
            int rx = (t >> 1) & 1;
            int ry = (t ^ rx) & 1;
            if (ry == 0) {
                if (rx == 1) { px = s - 1 - px; py = s - 1 - py; }
                int tmp = px; px = py; py = tmp;
            }
            px += s * rx; py += s * ry; t >>= 2;
        }
        lin[c] = py * 64 + px;
        flg[c] = (lin[c] < L) ? 1 : 0;
        cnt += flg[c];
    }
    sc[tid] = cnt; __syncthreads();
    for (int off = 1; off < 1024; off <<= 1) {
        int v = sc[tid];
        int a = (tid >= off) ? sc[tid - off] : 0;
        __syncthreads();
        sc[tid] = v + a;
        __syncthreads();
    }
    int base = sc[tid] - cnt;
    #pragma unroll
    for (int c = 0; c < 4; c++) if (flg[c]) perm_lds[base++] = lin[c];
    __syncthreads();
    for (int i = tid; i < L; i += 1024) inv_lds[perm_lds[i]] = i;
    __syncthreads();
    for (int p = tid; p < L; p += 1024) {
        int i = inv_lds[p];
        int s = pos + p;
        g_QROW[s] = pos + i;
        if ((i & (dil - 1)) == 0) {
            int kr = kbase + i / dil;
            g_KVROW[s] = kr;
            g_KVSRC[kr] = s;
        } else {
            g_KVROW[s] = -1;
        }
    }
}

// =====================================================================
// GEMM structure: BM=128, BN=256, BK=32, 512 threads (8 waves, 2Mx4N),
// per-wave 64x64 split as cols {wc*32, 128+wc*32}. LDS 48KB -> 3 blocks/CU.
// Counted vmcnt: P1-end vmcnt(2), P2-end vmcnt(1); raw s_barrier; 32 K-tiles,
// last peeled. Swizzle: stage piece (c&3)^(r&3); read piece lg^(lq&3)
// (all fragment-row offsets are multiples of 16, so row&3 == lq&3).
// =====================================================================

#define GEMM_DEFS                                                             \
    const int tid = threadIdx.x;                                              \
    const int lane = tid & 63;                                                \
    const int wid = tid >> 6;                                                 \
    const int lq = lane & 15, lg = lane >> 4;                                 \
    const int swz = lq & 3;                                                   \
    const int wr = wid >> 2, wc = wid & 3;

#define LD_A(cur)                                                             \
    _Pragma("unroll")                                                         \
    for (int mi = 0; mi < 4; mi++)                                            \
        af[mi] = *(const short8*)(&AT[cur][(wr * 64 + mi * 16 + lq) * 32 + ((lg ^ swz) << 3)]);
#define LD_B0(cur)                                                            \
    _Pragma("unroll")                                                         \
    for (int nj = 0; nj < 2; nj++)                                            \
        bf0[nj] = *(const short8*)(&BT[cur][(wc * 32 + nj * 16 + lq) * 32 + ((lg ^ swz) << 3)]);
#define LD_B1(cur)                                                            \
    _Pragma("unroll")                                                         \
    for (int nj = 0; nj < 2; nj++)                                            \
        bf1[nj] = *(const short8*)(&BT[cur][(128 + wc * 32 + nj * 16 + lq) * 32 + ((lg ^ swz) << 3)]);
#define MM0()                                                                 \
    __builtin_amdgcn_s_setprio(1);                                            \
    _Pragma("unroll")                                                         \
    for (int mi = 0; mi < 4; mi++)                                            \
        _Pragma("unroll")                                                     \
        for (int nj = 0; nj < 2; nj++)                                        \
            acc[mi][nj] = MFMA16(af[mi], bf0[nj], acc[mi][nj]);               \
    __builtin_amdgcn_s_setprio(0);
#define MM1()                                                                 \
    __builtin_amdgcn_s_setprio(1);                                            \
    _Pragma("unroll")                                                         \
    for (int mi = 0; mi < 4; mi++)                                            \
        _Pragma("unroll")                                                     \
        for (int nj = 0; nj < 2; nj++)                                        \
            acc[mi][nj + 2] = MFMA16(af[mi], bf1[nj], acc[mi][nj + 2]);       \
    __builtin_amdgcn_s_setprio(0);

// chunk geometry (BK=32): A tile 128x32 = 512 16B-chunks (1/thread),
// B tile 256x32 = 1024 chunks (2/thread, halves at tid and tid+512).
#define STG_A(b, kt_)  gl_lds16(sA0 + (kt_) * 32, &AT[b][tid * 8])
#define STG_B0(b, kt_) gl_lds16(sB[0] + (kt_) * 32, &BT[b][tid * 8])
#define STG_B1(b, kt_) gl_lds16(sB[1] + (kt_) * 32, &BT[b][(tid + 512) * 8])

#define GEMM_MAIN_LOOP                                                        \
    STG_A(0, 0); STG_B0(0, 0); STG_B1(0, 0);                                  \
    VMCNT(1);                                                                 \
    BAR();                                                                    \
    for (int kt = 0; kt < 31; kt++) {                                         \
        int cur = kt & 1, nxt = cur ^ 1;                                      \
        LD_A(cur); LD_B0(cur);                                                \
        STG_A(nxt, kt + 1); STG_B0(nxt, kt + 1);                              \
        MM0();                                                                \
        VMCNT(2);                                                             \
        BAR();                                                                \
        LD_B1(cur);                                                           \
        STG_B1(nxt, kt + 1);                                                  \
        MM1();                                                                \
        VMCNT(1);                                                             \
        BAR();                                                                \
    }                                                                         \
    LD_A(1); LD_B0(1);                                                        \
    MM0();                                                                    \
    VMCNT(0);                                                                 \
    BAR();                                                                    \
    LD_B1(1);                                                                 \
    MM1();

// ---------------- merged QKV GEMM: blocks [0,256)=Q, [256,512)=K/V ----------------
__global__ __launch_bounds__(512, 4) void qkv_merged(const float* __restrict__ bias) {
    __shared__ __align__(16) ushort AT[2][128 * 32];
    __shared__ __align__(16) ushort BT[2][256 * 32];
    GEMM_DEFS
    int b = blockIdx.x;
    bool isQ = b < 256;
    int bx, by;
    if (isQ) { bx = b & 63; by = b >> 6; }              // 64 x 4
    else     { int t = b - 256; bx = t & 31; by = t >> 5; }  // 32 x 8
    const int row0 = bx * 128, col0 = by * 256;

    // staging source addresses (BK=32): A chunk c=tid: row c>>2, piece (c&3)^(r&3)
    int rA = tid >> 2, pA = (tid & 3) ^ (rA & 3);
    long arow = isQ ? (row0 + rA) : g_KVSRC[row0 + rA];
    const ushort* sA0 = g_XB + arow * 1024 + pA * 8;
    int bcol0 = isQ ? col0 : (1024 + col0);
    const ushort* sB[2];
    #pragma unroll
    for (int j = 0; j < 2; j++) {
        int c = tid + 512 * j;
        int r = c >> 2, p = (c & 3) ^ (r & 3);
        sB[j] = g_WQB + (long)(bcol0 + r) * 1024 + p * 8;
    }

    fx4 acc[4][4] = {};
    short8 af[4], bf0[2], bf1[2];

    GEMM_MAIN_LOOP

    if (isQ) {
        #pragma unroll
        for (int mi = 0; mi < 4; mi++)
            #pragma unroll
            for (int r = 0; r < 4; r++) {
                int m = row0 + wr * 64 + mi * 16 + lg * 4 + r;
                int qr = g_QROW[m];
                #pragma unroll
                for (int nj = 0; nj < 4; nj++) {
                    int n = col0 + (nj >> 1) * 128 + wc * 32 + (nj & 1) * 16 + lq;
                    float val = acc[mi][nj][r] + bias[n];
                    int h = n >> 6, dd = n & 63;
                    g_QSEG[((long)h * 8192 + qr) * 64 + dd] = f2bf(val * QSCALE);
                }
            }
    } else {
        #pragma unroll
        for (int mi = 0; mi < 4; mi++)
            #pragma unroll
            for (int r = 0; r < 4; r++) {
                int m = row0 + wr * 64 + mi * 16 + lg * 4 + r;
                #pragma unroll
                for (int nj = 0; nj < 4; nj++) {
                    int n = col0 + (nj >> 1) * 128 + wc * 32 + (nj & 1) * 16 + lq;
                    float val = acc[mi][nj][r] + bias[1024 + n];
                    int h = (n >> 6) & 15, dd = n & 63;
                    if (n < 1024) g_KSEG[((long)h * 4096 + m) * 64 + dd] = f2bf(val);
                    else          g_VSEG[((long)h * 4096 + m) * 64 + dd] = f2bf(val);
                }
            }
    }
}

// ---------------- output GEMM: out[s][e] = attn[qrow[s]] @ Wout^T + b ----------------
__global__ __launch_bounds__(512, 4) void out_gemm8(const float* __restrict__ bias,
                                                    float* __restrict__ out) {
    __shared__ __align__(16) ushort AT[2][128 * 32];
    __shared__ __align__(16) ushort BT[2][256 * 32];
    GEMM_DEFS
    const int row0 = blockIdx.x * 128, col0 = blockIdx.y * 256;

    int rA = tid >> 2, pA = (tid & 3) ^ (rA & 3);
    const ushort* sA0 = g_ATTN + (long)g_QROW[row0 + rA] * 1024 + pA * 8;
    const ushort* sB[2];
    #pragma unroll
    for (int j = 0; j < 2; j++) {
        int c = tid + 512 * j;
        int r = c >> 2, p = (c & 3) ^ (r & 3);
        sB[j] = g_WOB + (long)(col0 + r) * 1024 + p * 8;
    }

    fx4 acc[4][4] = {};
    short8 af[4], bf0[2], bf1[2];

    GEMM_MAIN_LOOP

    #pragma unroll
    for (int mi = 0; mi < 4; mi++)
        #pragma unroll
        for (int r = 0; r < 4; r++) {
            int mm = row0 + wr * 64 + mi * 16 + lg * 4 + r;
            #pragma unroll
            for (int nj = 0; nj < 4; nj++) {
                int n = col0 + (nj >> 1) * 128 + wc * 32 + (nj & 1) * 16 + lq;
                out[(long)mm * 1024 + n] = acc[mi][nj][r] + bias[n];
            }
        }
}

// ---------------- V transpose: [h][row][d] -> [h][d][row] ----------------
__global__ __launch_bounds__(256) void vtrans_kernel() {
    __shared__ __align__(16) ushort tile[64 * 80];
    int b = blockIdx.x; int h = b >> 6; int rt = b & 63;
    const ushort* src = g_VSEG + ((long)h * 4096 + rt * 64) * 64;
    int tid = threadIdx.x;
    for (int c = tid; c < 512; c += 256) {
        int row = c >> 3, ch = c & 7;
        *(short8*)&tile[row * 80 + ch * 8] = *(const short8*)(src + row * 64 + ch * 8);
    }
    __syncthreads();
    for (int c = tid; c < 512; c += 256) {
        int d = c >> 3, oc = c & 7;
        ushort tmp[8];
        #pragma unroll
        for (int e = 0; e < 8; e++) tmp[e] = tile[(oc * 8 + e) * 80 + d];
        *(short8*)&g_VT[((long)h * 64 + d) * 4096 + rt * 64 + oc * 8] = *(short8*)tmp;
    }
}

// ---------------- attention: 32x32 MFMA, shiftless log2 softmax, lsum via ones-MFMA ----------------
// (R11 exact, known-good 58us.)
__global__ __launch_bounds__(256, 4) void attn_kernel() {
    __shared__ __align__(16) ushort Kt[2][64 * 64];
    __shared__ __align__(16) ushort Vt[2][64 * 64];
    int bid = blockIdx.x;
    int seg, h, qblk;
    if (bid < 256)      { seg = 0; h = bid >> 4;         qblk = bid & 15; }
    else if (bid < 512) { seg = 1; h = (bid - 256) >> 4; qblk = (bid - 256) & 15; }
    else                { seg = 2; h = (bid - 512) >> 5; qblk = (bid - 512) & 31; }
    int qbase = (seg == 0) ? 0 : (seg == 1) ? 2048 : 4096;
    int kbase = (seg == 0) ? 0 : (seg == 1) ? 2048 : 3072;
    int nkt   = (seg == 0) ? 32 : 16;

    int tid = threadIdx.x;
    int lane = tid & 63, wid = tid >> 6;
    int l5 = lane & 31, hi = lane >> 5;
    int sw7 = l5 & 7;
    int qrow0 = qbase + qblk * 128 + wid * 32;

    const ushort* kseg = g_KSEG + (long)h * 4096 * 64;
    const ushort* vtb0 = g_VT + (long)h * 64 * 4096 + kbase;

    int c0 = tid, c1 = tid + 256;
    int r0 = c0 >> 3, e0 = (c0 & 7) ^ (r0 & 7);
    int r1 = c1 >> 3, e1 = (c1 & 7) ^ (r1 & 7);
    const ushort* ka0 = kseg + (long)(kbase + r0) * 64 + e0 * 8;
    const ushort* ka1 = kseg + (long)(kbase + r1) * 64 + e1 * 8;
    const ushort* va0 = vtb0 + (long)r0 * 4096 + e0 * 8;
    const ushort* va1 = vtb0 + (long)r1 * 4096 + e1 * 8;

#define STAGE(b, kt_) do {                                                    \
        gl_lds16(ka0 + (long)(kt_) * 4096, &Kt[b][c0 * 8]);                   \
        gl_lds16(ka1 + (long)(kt_) * 4096, &Kt[b][c1 * 8]);                   \
        gl_lds16(va0 + (kt_) * 64, &Vt[b][c0 * 8]);                           \
        gl_lds16(va1 + (kt_) * 64, &Vt[b][c1 * 8]);                           \
    } while (0)

    const ushort* qp = g_QSEG + ((long)h * 8192 + qrow0 + l5) * 64;
    short8 qf[4];
    #pragma unroll
    for (int dc = 0; dc < 4; dc++)
        qf[dc] = *(const short8*)(qp + dc * 16 + hi * 8);

    short8 onesA;
    #pragma unroll
    for (int i = 0; i < 8; i++) onesA[i] = (short)0x3F80;

    STAGE(0, 0);
    VMCNT(0);
    __syncthreads();

    fx16 accO0 = {}, accO1 = {};
    fx16 lacc = {};

#define AITER(cur, kt_) do {                                                  \
        if ((kt_) + 1 < nkt) STAGE((cur) ^ 1, (kt_) + 1);                     \
        const ushort* Kc = Kt[cur];                                           \
        const ushort* Vc = Vt[cur];                                           \
        fx16 s0 = {}, s1 = {};                                                \
        __builtin_amdgcn_s_setprio(1);                                        \
        _Pragma("unroll")                                                     \
        for (int dc = 0; dc < 4; dc++) {                                      \
            short8 kf0 = *(const short8*)(Kc + l5 * 64 + (((2 * dc + hi) ^ sw7) << 3)); \
            short8 kf1 = *(const short8*)(Kc + (32 + l5) * 64 + (((2 * dc + hi) ^ sw7) << 3)); \
            s0 = MFMA32(kf0, qf[dc], s0);                                     \
            s1 = MFMA32(kf1, qf[dc], s1);                                     \
        }                                                                     \
        __builtin_amdgcn_s_setprio(0);                                        \
        uint dw0[8], dw1[8];                                                  \
        _Pragma("unroll")                                                     \
        for (int i = 0; i < 8; i++) {                                         \
            float p0 = exp2f_fast(s0[2 * i]);                                 \
            float p1 = exp2f_fast(s0[2 * i + 1]);                             \
            float p2 = exp2f_fast(s1[2 * i]);                                 \
            float p3 = exp2f_fast(s1[2 * i + 1]);                             \
            dw0[i] = cvt_pk_bf16(p0, p1);                                     \
            dw1[i] = cvt_pk_bf16(p2, p3);                                     \
        }                                                                     \
        short8 pb[4];                                                         \
        _Pragma("unroll")                                                     \
        for (int m4 = 0; m4 < 4; m4++) {                                      \
            int i0 = (m4 & 1) * 4;                                            \
            uint a0 = (m4 >> 1) ? dw1[i0] : dw0[i0];                          \
            uint a1 = (m4 >> 1) ? dw1[i0 + 1] : dw0[i0 + 1];                  \
            uint b0 = (m4 >> 1) ? dw1[i0 + 2] : dw0[i0 + 2];                  \
            uint b1 = (m4 >> 1) ? dw1[i0 + 3] : dw0[i0 + 3];                  \
            uint2v ra = __builtin_amdgcn_permlane32_swap(a0, b0, false, false); \
            uint2v rb = __builtin_amdgcn_permlane32_swap(a1, b1, false, false); \
            pb[m4] = mk8(ra[0], rb[0], ra[1], rb[1]);                         \
        }                                                                     \
        __builtin_amdgcn_s_setprio(1);                                        \
        _Pragma("unroll")                                                     \
        for (int m4 = 0; m4 < 4; m4++) {                                      \
            short8 vf0 = *(const short8*)(Vc + l5 * 64 + (((2 * m4 + hi) ^ sw7) << 3)); \
            short8 vf1 = *(const short8*)(Vc + (32 + l5) * 64 + (((2 * m4 + hi) ^ sw7) << 3)); \
            lacc = MFMA32(onesA, pb[m4], lacc);                               \
            accO0 = MFMA32(vf0, pb[m4], accO0);                               \
            accO1 = MFMA32(vf1, pb[m4], accO1);                               \
        }                                                                     \
        __builtin_amdgcn_s_setprio(0);                                        \
        VMCNT(0);                                                             \
        __syncthreads();                                                      \
    } while (0)

    for (int kt = 0; kt < nkt; kt += 2) {
        AITER(0, kt);
        AITER(1, kt + 1);
    }
#undef AITER
#undef STAGE

    float ri = 1.0f / lacc[0];
    ushort* op = g_ATTN + (long)(qrow0 + l5) * 1024 + h * 64;
    #pragma unroll
    for (int i = 0; i < 8; i++) {
        uint w0 = cvt_pk_bf16(accO0[2 * i] * ri, accO0[2 * i + 1] * ri);
        uint w1 = cvt_pk_bf16(accO1[2 * i] * ri, accO1[2 * i + 1] * ri);
        int d0 = 2 * (i & 1) + 8 * (i >> 1) + 4 * hi;
        *(uint*)(op + d0) = w0;
        *(uint*)(op + 32 + d0) = w1;
    }
}

extern "C" void kernel_launch(void* const* d_in, const int* in_sizes, int n_in,
                              void* d_out, int out_size, void* d_ws, size_t ws_size,
                              hipStream_t stream) {
    const float* x    = (const float*)d_in[0];
    const float* Wqkv = (const float*)d_in[1];
    const float* bqkv = (const float*)d_in[2];
    const float* Wout = (const float*)d_in[3];
    const float* bout = (const float*)d_in[4];
    float* out = (float*)d_out;
    (void)d_ws; (void)ws_size; (void)in_sizes; (void)n_in; (void)out_size;

    cvtperm_kernel<<<dim3(3075), dim3(1024), 0, stream>>>(x, Wqkv, Wout);
    qkv_merged<<<dim3(512), dim3(512), 0, stream>>>(bqkv);
    vtrans_kernel<<<dim3(1024), dim3(256), 0, stream>>>();
    attn_kernel<<<dim3(1024), dim3(256), 0, stream>>>();
    out_gemm8<<<dim3(64, 4), dim3(512), 0, stream>>>(bout, out);
}

// Round 17
// 149.598 us; speedup vs baseline: 1.0688x; 1.0688x over previous
//
#include <hip/hip_runtime.h>
#include <math.h>

typedef short short8 __attribute__((ext_vector_type(8)));
typedef float fx4 __attribute__((ext_vector_type(4)));
typedef float fx16 __attribute__((ext_vector_type(16)));
typedef unsigned short ushort;
typedef unsigned int uint;
typedef uint uint2v __attribute__((ext_vector_type(2)));

#define MFMA16(a, b, c) __builtin_amdgcn_mfma_f32_16x16x32_bf16(a, b, c, 0, 0, 0)
#define MFMA32(a, b, c) __builtin_amdgcn_mfma_f32_32x32x16_bf16(a, b, c, 0, 0, 0)

// segments: len {2048,2048,4096}, dil {1,2,4}; q rows packed at [0,2048,4096];
// k/v rows (dilated) packed at [0,2048,3072], total 4096.
// Q pre-scaled by (1/8)*log2(e); shiftless log2-domain softmax (P=exp2(S),
// uniform P scale cancels in O = P.V / P.1; |S|<128 always).
// R14 lesson: dispatch is round-robin (bid -> CU bid%256); simple maps are
// already balanced. R16 lesson: BK=32 halves LDS but introduces 4-way bank
// conflicts (64B row stride defeats 2-bit swizzle) and doubles barriers ->
// keep BK=64.
#define QSCALE 0.180336880f

#define BAR() do { asm volatile("" ::: "memory"); __builtin_amdgcn_s_barrier(); asm volatile("" ::: "memory"); } while (0)
#define VMCNT(n) asm volatile("s_waitcnt vmcnt(" #n ")" ::: "memory")

__device__ __forceinline__ ushort f2bf(float f) {
    union { float f; uint u; } v; v.f = f;
    uint r = v.u + 0x7fffu + ((v.u >> 16) & 1u);
    return (ushort)(r >> 16);
}

__device__ __forceinline__ float exp2f_fast(float x) {
    float r; asm("v_exp_f32 %0, %1" : "=v"(r) : "v"(x)); return r;
}

__device__ __forceinline__ uint cvt_pk_bf16(float lo, float hi) {
    uint r; asm("v_cvt_pk_bf16_f32 %0, %1, %2" : "=v"(r) : "v"(lo), "v"(hi)); return r;
}

__device__ __forceinline__ short8 mk8(uint a, uint b, uint c, uint d) {
    union { uint u[4]; short8 s; } x; x.u[0] = a; x.u[1] = b; x.u[2] = c; x.u[3] = d; return x.s;
}

__device__ __forceinline__ void gl_lds16(const void* g, void* l) {
    __builtin_amdgcn_global_load_lds(
        (const __attribute__((address_space(1))) void*)g,
        (__attribute__((address_space(3))) void*)l, 16, 0, 0);
}

// ---- scratch (static device globals; fully rewritten every call) ----
__device__ ushort g_XB[8192 * 1024];      // x bf16 [s][k]
__device__ ushort g_WQB[3072 * 1024];     // Wqkv bf16 [n][k]
__device__ ushort g_WOB[1024 * 1024];     // Wout bf16 [n][k]
__device__ ushort g_QSEG[16 * 8192 * 64]; // [h][qrow][d], permuted, scaled by QSCALE
__device__ ushort g_KSEG[16 * 4096 * 64]; // [h][krow][d], permuted+dilated
__device__ ushort g_VSEG[16 * 4096 * 64]; // [h][krow][d]
__device__ ushort g_VT[16 * 64 * 4096];   // [h][d][krow]  (V transposed)
__device__ ushort g_ATTN[8192 * 1024];    // [qrow][h*64+d] bf16 (permuted row space)
__device__ int g_QROW[8192];              // s -> permuted q row (global)
__device__ int g_KVROW[8192];             // s -> dilated k/v row (global) or -1
__device__ int g_KVSRC[4096];             // packed kv row -> source s (inverse of KVROW)

// ---------------- merged cvt (f32->bf16) + Hilbert perm kernel ----------------
__global__ __launch_bounds__(1024) void cvtperm_kernel(const float* __restrict__ x,
                                                       const float* __restrict__ wq,
                                                       const float* __restrict__ wo) {
    __shared__ int perm_lds[4096];
    __shared__ int inv_lds[4096];
    __shared__ int sc[1024];
    int b = blockIdx.x;
    int tid = threadIdx.x;
    if (b >= 3) {
        int idx = (b - 3) * 1024 + tid;
        const int NX = 8192 * 1024 / 4, NQ = 3072 * 1024 / 4;
        const float* s; ushort* d; int rel;
        if (idx < NX)           { s = x;  d = g_XB;  rel = idx; }
        else if (idx < NX + NQ) { s = wq; d = g_WQB; rel = idx - NX; }
        else                    { s = wo; d = g_WOB; rel = idx - NX - NQ; }
        fx4 v = *(const fx4*)(s + (long)rel * 4);
        uint lo = f2bf(v[0]) | ((uint)f2bf(v[1]) << 16);
        uint hi = f2bf(v[2]) | ((uint)f2bf(v[3]) << 16);
        uint2v w; w[0] = lo; w[1] = hi;
        *(uint2v*)(d + (long)rel * 4) = w;
        return;
    }
    int seg = b;
    int L     = (seg == 2) ? 4096 : 2048;
    int dil   = (seg == 0) ? 1 : (seg == 1) ? 2 : 4;
    int pos   = (seg == 0) ? 0 : (seg == 1) ? 2048 : 4096;
    int kbase = (seg == 0) ? 0 : (seg == 1) ? 2048 : 3072;

    int lin[4]; int flg[4]; int cnt = 0;
    #pragma unroll
    for (int c = 0; c < 4; c++) {
        int d = tid * 4 + c;
        int px = 0, py = 0, t = d;
        for (int s = 1; s < 64; s <<= 1) {
            int rx = (t >> 1) & 1;
            int ry = (t ^ rx) & 1;
            if (ry == 0) {
                if (rx == 1) { px = s - 1 - px; py = s - 1 - py; }
                int tmp = px; px = py; py = tmp;
            }
            px += s * rx; py += s * ry; t >>= 2;
        }
        lin[c] = py * 64 + px;
        flg[c] = (lin[c] < L) ? 1 : 0;
        cnt += flg[c];
    }
    sc[tid] = cnt; __syncthreads();
    for (int off = 1; off < 1024; off <<= 1) {
        int v = sc[tid];
        int a = (tid >= off) ? sc[tid - off] : 0;
        __syncthreads();
        sc[tid] = v + a;
        __syncthreads();
    }
    int base = sc[tid] - cnt;
    #pragma unroll
    for (int c = 0; c < 4; c++) if (flg[c]) perm_lds[base++] = lin[c];
    __syncthreads();
    for (int i = tid; i < L; i += 1024) inv_lds[perm_lds[i]] = i;
    __syncthreads();
    for (int p = tid; p < L; p += 1024) {
        int i = inv_lds[p];
        int s = pos + p;
        g_QROW[s] = pos + i;
        if ((i & (dil - 1)) == 0) {
            int kr = kbase + i / dil;
            g_KVROW[s] = kr;
            g_KVSRC[kr] = s;
        } else {
            g_KVROW[s] = -1;
        }
    }
}

// =====================================================================
// GEMM structure (proven R4): BM=128, BN=256, BK=64, 512 threads (8 waves,
// 2Mx4N), per-wave 64x64 split as cols {wc*32, 128+wc*32}. Counted vmcnt:
// P1-end vmcnt(4), P2-end vmcnt(2); raw s_barrier; last tile peeled.
// =====================================================================

#define GEMM_DEFS                                                             \
    const int tid = threadIdx.x;                                              \
    const int lane = tid & 63;                                                \
    const int wid = tid >> 6;                                                 \
    const int lq = lane & 15, lg = lane >> 4;                                 \
    const int swz = lq & 7;                                                   \
    const int wr = wid >> 2, wc = wid & 3;

#define LD_A(cur)                                                             \
    _Pragma("unroll")                                                         \
    for (int mi = 0; mi < 4; mi++)                                            \
        _Pragma("unroll")                                                     \
        for (int kk = 0; kk < 2; kk++)                                        \
            af[mi][kk] = *(const short8*)(&AT[cur][(wr * 64 + mi * 16 + lq) * 64 + (((kk * 4 + lg) ^ swz) << 3)]);
#define LD_B0(cur)                                                            \
    _Pragma("unroll")                                                         \
    for (int nj = 0; nj < 2; nj++)                                            \
        _Pragma("unroll")                                                     \
        for (int kk = 0; kk < 2; kk++)                                        \
            bf0[nj][kk] = *(const short8*)(&BT[cur][(wc * 32 + nj * 16 + lq) * 64 + (((kk * 4 + lg) ^ swz) << 3)]);
#define LD_B1(cur)                                                            \
    _Pragma("unroll")                                                         \
    for (int nj = 0; nj < 2; nj++)                                            \
        _Pragma("unroll")                                                     \
        for (int kk = 0; kk < 2; kk++)                                        \
            bf1[nj][kk] = *(const short8*)(&BT[cur][(128 + wc * 32 + nj * 16 + lq) * 64 + (((kk * 4 + lg) ^ swz) << 3)]);
#define MM0()                                                                 \
    __builtin_amdgcn_s_setprio(1);                                            \
    _Pragma("unroll")                                                         \
    for (int kk = 0; kk < 2; kk++)                                            \
        _Pragma("unroll")                                                     \
        for (int mi = 0; mi < 4; mi++)                                        \
            _Pragma("unroll")                                                 \
            for (int nj = 0; nj < 2; nj++)                                    \
                acc[mi][nj] = MFMA16(af[mi][kk], bf0[nj][kk], acc[mi][nj]);    \
    __builtin_amdgcn_s_setprio(0);
#define MM1()                                                                 \
    __builtin_amdgcn_s_setprio(1);                                            \
    _Pragma("unroll")                                                         \
    for (int kk = 0; kk < 2; kk++)                                            \
        _Pragma("unroll")                                                     \
        for (int mi = 0; mi < 4; mi++)                                        \
            _Pragma("unroll")                                                 \
            for (int nj = 0; nj < 2; nj++)                                    \
                acc[mi][nj + 2] = MFMA16(af[mi][kk], bf1[nj][kk], acc[mi][nj + 2]); \
    __builtin_amdgcn_s_setprio(0);

#define STG_A(b, kt_) do { gl_lds16(sA0 + (kt_) * 64, &AT[b][ca0 * 8]);      \
                           gl_lds16(sA1 + (kt_) * 64, &AT[b][ca1 * 8]); } while (0)
#define STG_B0(b, kt_) do { gl_lds16(sB[0] + (kt_) * 64, &BT[b][tid * 8]);   \
                            gl_lds16(sB[1] + (kt_) * 64, &BT[b][(tid + 512) * 8]); } while (0)
#define STG_B1(b, kt_) do { gl_lds16(sB[2] + (kt_) * 64, &BT[b][(tid + 1024) * 8]); \
                            gl_lds16(sB[3] + (kt_) * 64, &BT[b][(tid + 1536) * 8]); } while (0)

#define GEMM_MAIN_LOOP                                                        \
    STG_A(0, 0); STG_B0(0, 0); STG_B1(0, 0);                                  \
    VMCNT(2);                                                                 \
    BAR();                                                                    \
    for (int kt = 0; kt < 15; kt++) {                                         \
        int cur = kt & 1, nxt = cur ^ 1;                                      \
        LD_A(cur); LD_B0(cur);                                                \
        STG_A(nxt, kt + 1); STG_B0(nxt, kt + 1);                              \
        MM0();                                                                \
        VMCNT(4);                                                             \
        BAR();                                                                \
        LD_B1(cur);                                                           \
        STG_B1(nxt, kt + 1);                                                  \
        MM1();                                                                \
        VMCNT(2);                                                             \
        BAR();                                                                \
    }                                                                         \
    LD_A(1); LD_B0(1);                                                        \
    MM0();                                                                    \
    VMCNT(0);                                                                 \
    BAR();                                                                    \
    LD_B1(1);                                                                 \
    MM1();

// ---------------- merged QKV GEMM: blocks [0,256)=Q, [256,512)=K/V ----------------
__global__ __launch_bounds__(512, 2) void qkv_merged(const float* __restrict__ bias) {
    __shared__ __align__(16) ushort AT[2][128 * 64];
    __shared__ __align__(16) ushort BT[2][256 * 64];
    GEMM_DEFS
    int b = blockIdx.x;
    bool isQ = b < 256;
    int bx, by;
    if (isQ) { bx = b & 63; by = b >> 6; }              // 64 x 4
    else     { int t = b - 256; bx = t & 31; by = t >> 5; }  // 32 x 8
    const int row0 = bx * 128, col0 = by * 256;

    int ca0 = tid, ca1 = tid + 512;
    int ra0 = ca0 >> 3, pa0 = (ca0 & 7) ^ (ra0 & 7);
    int ra1 = ca1 >> 3, pa1 = (ca1 & 7) ^ (ra1 & 7);
    long arow0 = isQ ? (row0 + ra0) : g_KVSRC[row0 + ra0];
    long arow1 = isQ ? (row0 + ra1) : g_KVSRC[row0 + ra1];
    const ushort* sA0 = g_XB + arow0 * 1024 + pa0 * 8;
    const ushort* sA1 = g_XB + arow1 * 1024 + pa1 * 8;
    int bcol0 = isQ ? col0 : (1024 + col0);
    const ushort* sB[4];
    #pragma unroll
    for (int j = 0; j < 4; j++) {
        int c = tid + 512 * j;
        int r = c >> 3, p = (c & 7) ^ (r & 7);
        sB[j] = g_WQB + (long)(bcol0 + r) * 1024 + p * 8;
    }

    fx4 acc[4][4] = {};
    short8 af[4][2], bf0[2][2], bf1[2][2];

    GEMM_MAIN_LOOP

    if (isQ) {
        #pragma unroll
        for (int mi = 0; mi < 4; mi++)
            #pragma unroll
            for (int r = 0; r < 4; r++) {
                int m = row0 + wr * 64 + mi * 16 + lg * 4 + r;
                int qr = g_QROW[m];
                #pragma unroll
                for (int nj = 0; nj < 4; nj++) {
                    int n = col0 + (nj >> 1) * 128 + wc * 32 + (nj & 1) * 16 + lq;
                    float val = acc[mi][nj][r] + bias[n];
                    int h = n >> 6, dd = n & 63;
                    g_QSEG[((long)h * 8192 + qr) * 64 + dd] = f2bf(val * QSCALE);
                }
            }
    } else {
        #pragma unroll
        for (int mi = 0; mi < 4; mi++)
            #pragma unroll
            for (int r = 0; r < 4; r++) {
                int m = row0 + wr * 64 + mi * 16 + lg * 4 + r;
                #pragma unroll
                for (int nj = 0; nj < 4; nj++) {
                    int n = col0 + (nj >> 1) * 128 + wc * 32 + (nj & 1) * 16 + lq;
                    float val = acc[mi][nj][r] + bias[1024 + n];
                    int h = (n >> 6) & 15, dd = n & 63;
                    if (n < 1024) g_KSEG[((long)h * 4096 + m) * 64 + dd] = f2bf(val);
                    else          g_VSEG[((long)h * 4096 + m) * 64 + dd] = f2bf(val);
                }
            }
    }
}

// ---------------- output GEMM: out[s][e] = attn[qrow[s]] @ Wout^T + b ----------------
__global__ __launch_bounds__(512, 2) void out_gemm8(const float* __restrict__ bias,
                                                    float* __restrict__ out) {
    __shared__ __align__(16) ushort AT[2][128 * 64];
    __shared__ __align__(16) ushort BT[2][256 * 64];
    GEMM_DEFS
    const int row0 = blockIdx.x * 128, col0 = blockIdx.y * 256;

    int ca0 = tid, ca1 = tid + 512;
    int ra0 = ca0 >> 3, pa0 = (ca0 & 7) ^ (ra0 & 7);
    int ra1 = ca1 >> 3, pa1 = (ca1 & 7) ^ (ra1 & 7);
    const ushort* sA0 = g_ATTN + (long)g_QROW[row0 + ra0] * 1024 + pa0 * 8;
    const ushort* sA1 = g_ATTN + (long)g_QROW[row0 + ra1] * 1024 + pa1 * 8;
    const ushort* sB[4];
    #pragma unroll
    for (int j = 0; j < 4; j++) {
        int c = tid + 512 * j;
        int r = c >> 3, p = (c & 7) ^ (r & 7);
        sB[j] = g_WOB + (long)(col0 + r) * 1024 + p * 8;
    }

    fx4 acc[4][4] = {};
    short8 af[4][2], bf0[2][2], bf1[2][2];

    GEMM_MAIN_LOOP

    #pragma unroll
    for (int mi = 0; mi < 4; mi++)
        #pragma unroll
        for (int r = 0; r < 4; r++) {
            int mm = row0 + wr * 64 + mi * 16 + lg * 4 + r;
            #pragma unroll
            for (int nj = 0; nj < 4; nj++) {
                int n = col0 + (nj >> 1) * 128 + wc * 32 + (nj & 1) * 16 + lq;
                out[(long)mm * 1024 + n] = acc[mi][nj][r] + bias[n];
            }
        }
}

// ---------------- V transpose: [h][row][d] -> [h][d][row] ----------------
__global__ __launch_bounds__(256) void vtrans_kernel() {
    __shared__ __align__(16) ushort tile[64 * 80];
    int b = blockIdx.x; int h = b >> 6; int rt = b & 63;
    const ushort* src = g_VSEG + ((long)h * 4096 + rt * 64) * 64;
    int tid = threadIdx.x;
    for (int c = tid; c < 512; c += 256) {
        int row = c >> 3, ch = c & 7;
        *(short8*)&tile[row * 80 + ch * 8] = *(const short8*)(src + row * 64 + ch * 8);
    }
    __syncthreads();
    for (int c = tid; c < 512; c += 256) {
        int d = c >> 3, oc = c & 7;
        ushort tmp[8];
        #pragma unroll
        for (int e = 0; e < 8; e++) tmp[e] = tile[(oc * 8 + e) * 80 + d];
        *(short8*)&g_VT[((long)h * 64 + d) * 4096 + rt * 64 + oc * 8] = *(short8*)tmp;
    }
}

// ---------------- attention: 32x32 MFMA, shiftless log2 softmax, lsum via ones-MFMA ----------------
// (R11 exact, known-good 58us.) Wave = 32 q rows. S^T via mfma32(K,Q): lane
// (q=l5, hi) holds P[q][key], key=(r&3)+8(r>>2)+4hi per 32-key block.
// P = exp2(S); PV B-operand via permlane32_swap ((x,y)=swap(a,b):
// x={lo:own a, hi:partner b}); lsum via ones-MFMA; kt loop unrolled x2.
__global__ __launch_bounds__(256, 4) void attn_kernel() {
    __shared__ __align__(16) ushort Kt[2][64 * 64];
    __shared__ __align__(16) ushort Vt[2][64 * 64];
    int bid = blockIdx.x;
    int seg, h, qblk;
    if (bid < 256)      { seg = 0; h = bid >> 4;         qblk = bid & 15; }
    else if (bid < 512) { seg = 1; h = (bid - 256) >> 4; qblk = (bid - 256) & 15; }
    else                { seg = 2; h = (bid - 512) >> 5; qblk = (bid - 512) & 31; }
    int qbase = (seg == 0) ? 0 : (seg == 1) ? 2048 : 4096;
    int kbase = (seg == 0) ? 0 : (seg == 1) ? 2048 : 3072;
    int nkt   = (seg == 0) ? 32 : 16;

    int tid = threadIdx.x;
    int lane = tid & 63, wid = tid >> 6;
    int l5 = lane & 31, hi = lane >> 5;
    int sw7 = l5 & 7;
    int qrow0 = qbase + qblk * 128 + wid * 32;

    const ushort* kseg = g_KSEG + (long)h * 4096 * 64;
    const ushort* vtb0 = g_VT + (long)h * 64 * 4096 + kbase;

    int c0 = tid, c1 = tid + 256;
    int r0 = c0 >> 3, e0 = (c0 & 7) ^ (r0 & 7);
    int r1 = c1 >> 3, e1 = (c1 & 7) ^ (r1 & 7);
    const ushort* ka0 = kseg + (long)(kbase + r0) * 64 + e0 * 8;
    const ushort* ka1 = kseg + (long)(kbase + r1) * 64 + e1 * 8;
    const ushort* va0 = vtb0 + (long)r0 * 4096 + e0 * 8;
    const ushort* va1 = vtb0 + (long)r1 * 4096 + e1 * 8;

#define STAGE(b, kt_) do {                                                    \
        gl_lds16(ka0 + (long)(kt_) * 4096, &Kt[b][c0 * 8]);                   \
        gl_lds16(ka1 + (long)(kt_) * 4096, &Kt[b][c1 * 8]);                   \
        gl_lds16(va0 + (kt_) * 64, &Vt[b][c0 * 8]);                           \
        gl_lds16(va1 + (kt_) * 64, &Vt[b][c1 * 8]);                           \
    } while (0)

    const ushort* qp = g_QSEG + ((long)h * 8192 + qrow0 + l5) * 64;
    short8 qf[4];
    #pragma unroll
    for (int dc = 0; dc < 4; dc++)
        qf[dc] = *(const short8*)(qp + dc * 16 + hi * 8);

    short8 onesA;
    #pragma unroll
    for (int i = 0; i < 8; i++) onesA[i] = (short)0x3F80;

    STAGE(0, 0);
    VMCNT(0);
    __syncthreads();

    fx16 accO0 = {}, accO1 = {};
    fx16 lacc = {};

#define AITER(cur, kt_) do {                                                  \
        if ((kt_) + 1 < nkt) STAGE((cur) ^ 1, (kt_) + 1);                     \
        const ushort* Kc = Kt[cur];                                           \
        const ushort* Vc = Vt[cur];                                           \
        fx16 s0 = {}, s1 = {};                                                \
        __builtin_amdgcn_s_setprio(1);                                        \
        _Pragma("unroll")                                                     \
        for (int dc = 0; dc < 4; dc++) {                                      \
            short8 kf0 = *(const short8*)(Kc + l5 * 64 + (((2 * dc + hi) ^ sw7) << 3)); \
            short8 kf1 = *(const short8*)(Kc + (32 + l5) * 64 + (((2 * dc + hi) ^ sw7) << 3)); \
            s0 = MFMA32(kf0, qf[dc], s0);                                     \
            s1 = MFMA32(kf1, qf[dc], s1);                                     \
        }                                                                     \
        __builtin_amdgcn_s_setprio(0);                                        \
        uint dw0[8], dw1[8];                                                  \
        _Pragma("unroll")                                                     \
        for (int i = 0; i < 8; i++) {                                         \
            float p0 = exp2f_fast(s0[2 * i]);                                 \
            float p1 = exp2f_fast(s0[2 * i + 1]);                             \
            float p2 = exp2f_fast(s1[2 * i]);                                 \
            float p3 = exp2f_fast(s1[2 * i + 1]);                             \
            dw0[i] = cvt_pk_bf16(p0, p1);                                     \
            dw1[i] = cvt_pk_bf16(p2, p3);                                     \
        }                                                                     \
        short8 pb[4];                                                         \
        _Pragma("unroll")                                                     \
        for (int m4 = 0; m4 < 4; m4++) {                                      \
            int i0 = (m4 & 1) * 4;                                            \
            uint a0 = (m4 >> 1) ? dw1[i0] : dw0[i0];                          \
            uint a1 = (m4 >> 1) ? dw1[i0 + 1] : dw0[i0 + 1];                  \
            uint b0 = (m4 >> 1) ? dw1[i0 + 2] : dw0[i0 + 2];                  \
            uint b1 = (m4 >> 1) ? dw1[i0 + 3] : dw0[i0 + 3];                  \
            uint2v ra = __builtin_amdgcn_permlane32_swap(a0, b0, false, false); \
            uint2v rb = __builtin_amdgcn_permlane32_swap(a1, b1, false, false); \
            pb[m4] = mk8(ra[0], rb[0], ra[1], rb[1]);                         \
        }                                                                     \
        __builtin_amdgcn_s_setprio(1);                                        \
        _Pragma("unroll")                                                     \
        for (int m4 = 0; m4 < 4; m4++) {                                      \
            short8 vf0 = *(const short8*)(Vc + l5 * 64 + (((2 * m4 + hi) ^ sw7) << 3)); \
            short8 vf1 = *(const short8*)(Vc + (32 + l5) * 64 + (((2 * m4 + hi) ^ sw7) << 3)); \
            lacc = MFMA32(onesA, pb[m4], lacc);                               \
            accO0 = MFMA32(vf0, pb[m4], accO0);                               \
            accO1 = MFMA32(vf1, pb[m4], accO1);                               \
        }                                                                     \
        __builtin_amdgcn_s_setprio(0);                                        \
        VMCNT(0);                                                             \
        __syncthreads();                                                      \
    } while (0)

    for (int kt = 0; kt < nkt; kt += 2) {
        AITER(0, kt);
        AITER(1, kt + 1);
    }
#undef AITER
#undef STAGE

    float ri = 1.0f / lacc[0];
    ushort* op = g_ATTN + (long)(qrow0 + l5) * 1024 + h * 64;
    #pragma unroll
    for (int i = 0; i < 8; i++) {
        uint w0 = cvt_pk_bf16(accO0[2 * i] * ri, accO0[2 * i + 1] * ri);
        uint w1 = cvt_pk_bf16(accO1[2 * i] * ri, accO1[2 * i + 1] * ri);
        int d0 = 2 * (i & 1) + 8 * (i >> 1) + 4 * hi;
        *(uint*)(op + d0) = w0;
        *(uint*)(op + 32 + d0) = w1;
    }
}

extern "C" void kernel_launch(void* const* d_in, const int* in_sizes, int n_in,
                              void* d_out, int out_size, void* d_ws, size_t ws_size,
                              hipStream_t stream) {
    const float* x    = (const float*)d_in[0];
    const float* Wqkv = (const float*)d_in[1];
    const float* bqkv = (const float*)d_in[2];
    const float* Wout = (const float*)d_in[3];
    const float* bout = (const float*)d_in[4];
    float* out = (float*)d_out;
    (void)d_ws; (void)ws_size; (void)in_sizes; (void)n_in; (void)out_size;

    cvtperm_kernel<<<dim3(3075), dim3(1024), 0, stream>>>(x, Wqkv, Wout);
    qkv_merged<<<dim3(512), dim3(512), 0, stream>>>(bqkv);
    vtrans_kernel<<<dim3(1024), dim3(256), 0, stream>>>();
    attn_kernel<<<dim3(1024), dim3(256), 0, stream>>>();
    out_gemm8<<<dim3(64, 4), dim3(512), 0, stream>>>(bout, out);
}